// Round 1
// baseline (49.792 us; speedup 1.0000x reference)
//
#include <hip/hip_runtime.h>

// Problem constants (from the reference)
constexpr int Bc = 16;
constexpr int Ac = 3;
constexpr int Cc = 80;
constexpr int Hc = 76;
constexpr int Wc = 76;
constexpr int HWc = Hc * Wc;          // 5776
constexpr int Nc  = Ac * HWc;         // 17328
constexpr float SCALE_XY = 1.2f;

// anchors reshaped (A,2): (w,h) pairs
__constant__ float kAnchorW[Ac] = {1.5f, 2.375f, 5.0f};
__constant__ float kAnchorH[Ac] = {2.0f, 4.5f, 3.5f};

__device__ __forceinline__ float sigmoidf_(float x) {
    return 1.0f / (1.0f + __expf(-x));
}

__global__ __launch_bounds__(256) void yolo_kernel(
    const float* __restrict__ in,   // [B, A*(5+C), H, W]
    float* __restrict__ boxes,      // [B, N, 1, 4]
    float* __restrict__ confs)      // [B, N, C]
{
    const int tid = blockIdx.x * 256 + threadIdx.x;
    constexpr int TOTAL = Bc * Ac * HWc;
    if (tid >= TOTAL) return;

    const int hw = tid % HWc;
    const int ba = tid / HWc;
    const int a  = ba % Ac;
    const int b  = ba / Ac;

    const int x = hw % Wc;
    const int y = hw / Wc;

    // input base pointer for this (b, a, hw); channel stride = HWc
    const float* p = in + ((size_t)b * (Ac * (5 + Cc)) + (size_t)a * (5 + Cc)) * HWc + hw;

    const float o0 = p[0 * HWc];
    const float o1 = p[1 * HWc];
    const float o2 = p[2 * HWc];
    const float o3 = p[3 * HWc];
    const float o4 = p[4 * HWc];

    // ---- class logits: registers, stable softmax ----
    float v[Cc];
    float m = -3.402823466e+38f;
    #pragma unroll
    for (int c = 0; c < Cc; ++c) {
        v[c] = p[(5 + c) * HWc];
        m = fmaxf(m, v[c]);
    }
    float s = 0.0f;
    #pragma unroll
    for (int c = 0; c < Cc; ++c) {
        v[c] = __expf(v[c] - m);
        s += v[c];
    }
    const float det  = sigmoidf_(o4);
    const float scale = det / s;       // softmax normalize fused with det_conf multiply

    // ---- boxes ----
    const float bx = (sigmoidf_(o0) * SCALE_XY - 0.5f * (SCALE_XY - 1.0f) + (float)x) * (1.0f / (float)Wc);
    const float by = (sigmoidf_(o1) * SCALE_XY - 0.5f * (SCALE_XY - 1.0f) + (float)y) * (1.0f / (float)Hc);
    const float bw = __expf(o2) * kAnchorW[a] * (1.0f / (float)Wc);
    const float bh = __expf(o3) * kAnchorH[a] * (1.0f / (float)Hc);

    const float bx1 = bx - bw * 0.5f;
    const float by1 = by - bh * 0.5f;
    const float bx2 = bx1 + bw;
    const float by2 = by1 + bh;

    const int n = a * HWc + hw;   // detection index within batch

    float4 box = make_float4(bx1, by1, bx2, by2);
    *reinterpret_cast<float4*>(&boxes[((size_t)b * Nc + n) * 4]) = box;

    float* cp = &confs[((size_t)b * Nc + n) * Cc];
    #pragma unroll
    for (int c = 0; c < Cc; c += 4) {
        float4 t = make_float4(v[c] * scale, v[c + 1] * scale, v[c + 2] * scale, v[c + 3] * scale);
        *reinterpret_cast<float4*>(&cp[c]) = t;
    }
}

extern "C" void kernel_launch(void* const* d_in, const int* in_sizes, int n_in,
                              void* d_out, int out_size, void* d_ws, size_t ws_size,
                              hipStream_t stream) {
    const float* in = (const float*)d_in[0];
    float* out = (float*)d_out;

    float* boxes = out;                                  // B*N*1*4 floats
    float* confs = out + (size_t)Bc * Nc * 4;            // B*N*C floats

    constexpr int TOTAL = Bc * Ac * HWc;                 // 277248 = 1083 * 256
    const int blocks = (TOTAL + 255) / 256;
    yolo_kernel<<<blocks, 256, 0, stream>>>(in, boxes, confs);
}

// Round 2
// 42.598 us; speedup vs baseline: 1.1689x; 1.1689x over previous
//
#include <hip/hip_runtime.h>

// Problem constants (from the reference)
constexpr int Bc = 16;
constexpr int Ac = 3;
constexpr int Cc = 80;
constexpr int Hc = 76;
constexpr int Wc = 76;
constexpr int HWc = Hc * Wc;          // 5776
constexpr int Nc  = Ac * HWc;         // 17328
constexpr float SCALE_XY = 1.2f;

constexpr int Q   = 4;                // lanes cooperating per location
constexpr int CPT = Cc / Q;           // classes per thread = 20

// anchors reshaped (A,2): (w,h) pairs
__constant__ float kAnchorW[Ac] = {1.5f, 2.375f, 5.0f};
__constant__ float kAnchorH[Ac] = {2.0f, 4.5f, 3.5f};

__device__ __forceinline__ float sigmoidf_(float x) {
    return 1.0f / (1.0f + __expf(-x));
}

__global__ __launch_bounds__(256) void yolo_kernel(
    const float* __restrict__ in,   // [B, A*(5+C), H, W]
    float* __restrict__ boxes,      // [B, N, 1, 4]
    float* __restrict__ confs)      // [B, N, C]
{
    const int tid = blockIdx.x * 256 + threadIdx.x;
    const int loc = tid >> 2;          // location index in [0, B*A*HW)
    const int q   = tid & 3;           // class-quarter handled by this lane

    const int hw = loc % HWc;
    const int ba = loc / HWc;
    const int a  = ba % Ac;
    const int b  = ba / Ac;

    const int x = hw % Wc;
    const int y = hw / Wc;

    // input base pointer for this (b, a, hw); channel stride = HWc
    const float* p = in + ((size_t)(b * Ac + a) * (5 + Cc)) * HWc + hw;

    // ---- this lane's 20 class logits ----
    float v[CPT];
    float m = -3.402823466e+38f;
    #pragma unroll
    for (int c = 0; c < CPT; ++c) {
        v[c] = p[(5 + q * CPT + c) * HWc];
        m = fmaxf(m, v[c]);
    }
    // max across the 4-lane group
    m = fmaxf(m, __shfl_xor(m, 1));
    m = fmaxf(m, __shfl_xor(m, 2));

    float s = 0.0f;
    #pragma unroll
    for (int c = 0; c < CPT; ++c) {
        v[c] = __expf(v[c] - m);
        s += v[c];
    }
    // sum across the 4-lane group
    s += __shfl_xor(s, 1);
    s += __shfl_xor(s, 2);

    const float o4   = p[4 * HWc];           // same addr for the 4 lanes -> broadcast
    const float det  = sigmoidf_(o4);
    const float scale = det / s;

    const int n = a * HWc + hw;              // detection index within batch

    // ---- conf writes: each lane writes 80 contiguous bytes; the 4-lane
    // group covers the full 320B row ----
    float* cp = &confs[((size_t)b * Nc + n) * Cc + q * CPT];
    #pragma unroll
    for (int c = 0; c < CPT; c += 4) {
        float4 t = make_float4(v[c] * scale, v[c + 1] * scale,
                               v[c + 2] * scale, v[c + 3] * scale);
        *reinterpret_cast<float4*>(&cp[c]) = t;
    }

    // ---- boxes: one lane per location ----
    if (q == 0) {
        const float o0 = p[0 * HWc];
        const float o1 = p[1 * HWc];
        const float o2 = p[2 * HWc];
        const float o3 = p[3 * HWc];

        const float bx = (sigmoidf_(o0) * SCALE_XY - 0.5f * (SCALE_XY - 1.0f) + (float)x) * (1.0f / (float)Wc);
        const float by = (sigmoidf_(o1) * SCALE_XY - 0.5f * (SCALE_XY - 1.0f) + (float)y) * (1.0f / (float)Hc);
        const float bw = __expf(o2) * kAnchorW[a] * (1.0f / (float)Wc);
        const float bh = __expf(o3) * kAnchorH[a] * (1.0f / (float)Hc);

        const float bx1 = bx - bw * 0.5f;
        const float by1 = by - bh * 0.5f;
        const float bx2 = bx1 + bw;
        const float by2 = by1 + bh;

        float4 box = make_float4(bx1, by1, bx2, by2);
        *reinterpret_cast<float4*>(&boxes[((size_t)b * Nc + n) * 4]) = box;
    }
}

extern "C" void kernel_launch(void* const* d_in, const int* in_sizes, int n_in,
                              void* d_out, int out_size, void* d_ws, size_t ws_size,
                              hipStream_t stream) {
    const float* in = (const float*)d_in[0];
    float* out = (float*)d_out;

    float* boxes = out;                                  // B*N*1*4 floats
    float* confs = out + (size_t)Bc * Nc * 4;            // B*N*C floats

    constexpr int TOTAL_THREADS = Bc * Ac * HWc * Q;     // 1,108,992 = 4332 * 256
    const int blocks = TOTAL_THREADS / 256;
    yolo_kernel<<<blocks, 256, 0, stream>>>(in, boxes, confs);
}